// Round 6
// baseline (241.946 us; speedup 1.0000x reference)
//
#include <hip/hip_runtime.h>

typedef unsigned short u16;
typedef float f32x4 __attribute__((ext_vector_type(4)));
typedef __bf16 bf16x8 __attribute__((ext_vector_type(8)));

__device__ __forceinline__ u16 f2bf(float f) {
  union { float f; unsigned u; } v; v.f = f;
  unsigned r = (v.u + 0x7fffu + ((v.u >> 16) & 1u)) >> 16;
  return (u16)r;
}
__device__ __forceinline__ float bf2f(u16 h) {
  union { unsigned u; float f; } v; v.u = ((unsigned)h) << 16; return v.f;
}
// pack two f32 -> one u32 of 2x bf16 (lo=a, hi=b) in pure C (no ISA assumption)
__device__ __forceinline__ unsigned pack2bf(float a, float b) {
  return ((unsigned)f2bf(b) << 16) | (unsigned)f2bf(a);
}

#define GLOAD16(gp, lp)                                                        \
  __builtin_amdgcn_global_load_lds(                                            \
      (const __attribute__((address_space(1))) void*)(gp),                     \
      (__attribute__((address_space(3))) void*)(lp), 16, 0, 0)

#define LOG2E 1.4426950408889634f

// ---------------------------------------------------------------- cast weights
__global__ __launch_bounds__(256) void cast_w_kernel(
    const float* __restrict__ wq, const float* __restrict__ wk,
    const float* __restrict__ wv, const float* __restrict__ wg,
    const float* __restrict__ wo, u16* __restrict__ wcat, u16* __restrict__ wobf)
{
  int idx = blockIdx.x * 256 + threadIdx.x;   // 320 blocks -> 81920 threads
  int e = idx * 4;                            // 4 floats each
  int row = e >> 8;
  int col = e & 255;
  const float* src = (row < 256)  ? (wq + (size_t)row * 256)
                   : (row < 512)  ? (wk + (size_t)(row - 256) * 256)
                   : (row < 768)  ? (wv + (size_t)(row - 512) * 256)
                   : (row < 1024) ? (wg + (size_t)(row - 768) * 256)
                                  : (wo + (size_t)(row - 1024) * 256);
  float4 v = *(const float4*)(src + col);
  ushort4 o;
  o.x = f2bf(v.x); o.y = f2bf(v.y); o.z = f2bf(v.z); o.w = f2bf(v.w);
  if (row < 1024) *(ushort4*)(wcat + e) = o;
  else            *(ushort4*)(wobf + (e - 262144)) = o;
}

// ---------------------------------------------------------------- LN(msa)->bf16
__global__ __launch_bounds__(256) void ln_msa_kernel(
    const float* __restrict__ x, const float* __restrict__ sc,
    const float* __restrict__ bi, u16* __restrict__ mo)
{
  const int row  = blockIdx.x * 4 + (threadIdx.x >> 6);
  const int lane = threadIdx.x & 63;
  const float4 v = *(const float4*)(x + (size_t)row * 256 + lane * 4);
  float s = v.x + v.y + v.z + v.w;
  #pragma unroll
  for (int off = 1; off < 64; off <<= 1) s += __shfl_xor(s, off);
  const float mu = s * 0.00390625f;
  const float d0 = v.x - mu, d1 = v.y - mu, d2 = v.z - mu, d3 = v.w - mu;
  float vs = d0*d0 + d1*d1 + d2*d2 + d3*d3;
  #pragma unroll
  for (int off = 1; off < 64; off <<= 1) vs += __shfl_xor(vs, off);
  const float rstd = rsqrtf(vs * 0.00390625f + 1e-5f);
  const float4 scv = *(const float4*)(sc + lane * 4);
  const float4 biv = *(const float4*)(bi + lane * 4);
  ushort4 o;
  o.x = f2bf(d0 * rstd * scv.x + biv.x);
  o.y = f2bf(d1 * rstd * scv.y + biv.y);
  o.z = f2bf(d2 * rstd * scv.z + biv.z);
  o.w = f2bf(d3 * rstd * scv.w + biv.w);
  *(ushort4*)(mo + (size_t)row * 256 + lane * 4) = o;
}

// ------------------------------------------- LN(pair) + einsum('ijc,hc->hij')
// Writes bias NATURAL layout, bf16, pre-scaled by log2(e): biasQ[h][i=q][j=key]
__global__ __launch_bounds__(256) void ln_pair_bias_kernel(
    const float* __restrict__ pair, const float* __restrict__ sc,
    const float* __restrict__ bi, const float* __restrict__ wb,
    u16* __restrict__ biasQ)
{
  __shared__ float swb[1024];
  #pragma unroll
  for (int i = 0; i < 4; ++i) swb[i * 256 + threadIdx.x] = wb[i * 256 + threadIdx.x];
  __syncthreads();
  const int ij   = blockIdx.x * 4 + (threadIdx.x >> 6);   // 0..65535
  const int lane = threadIdx.x & 63;
  const float2 v = *(const float2*)(pair + (size_t)ij * 128 + lane * 2);
  float s = v.x + v.y;
  #pragma unroll
  for (int off = 1; off < 64; off <<= 1) s += __shfl_xor(s, off);
  const float mu = s * 0.0078125f;
  const float d0 = v.x - mu, d1 = v.y - mu;
  float vs = d0*d0 + d1*d1;
  #pragma unroll
  for (int off = 1; off < 64; off <<= 1) vs += __shfl_xor(vs, off);
  const float rstd = rsqrtf(vs * 0.0078125f + 1e-5f);
  const float2 scv = *(const float2*)(sc + lane * 2);
  const float2 biv = *(const float2*)(bi + lane * 2);
  const float z0 = d0 * rstd * scv.x + biv.x;
  const float z1 = d1 * rstd * scv.y + biv.y;
  float a[8];
  #pragma unroll
  for (int hh = 0; hh < 8; ++hh)
    a[hh] = z0 * swb[hh * 128 + lane * 2] + z1 * swb[hh * 128 + lane * 2 + 1];
  #pragma unroll
  for (int off = 1; off < 64; off <<= 1) {
    #pragma unroll
    for (int hh = 0; hh < 8; ++hh) a[hh] += __shfl_xor(a[hh], off);
  }
  if (lane == 0) {
    const int i = ij >> 8, j = ij & 255;
    #pragma unroll
    for (int hh = 0; hh < 8; ++hh) biasQ[hh * 65536 + i * 256 + j] = f2bf(a[hh] * LOG2E);
  }
}

// ------------------------------- persistent B-stationary small-K GEMM
// Grid 512 (2 blocks/CU). Block: stage B tile (64 cols x 256 K = 32 KB) once,
// then UNITS row-tiles of 128 rows with ping-pong register-prefetched A frags.
// A rows partitioned per-XCD (2 MB slice -> L2 resident).
// EPI 0: qkvg epilogue (scale q by log2e/sqrt32, sigmoid gate); EPI 1: residual
template<int EPI, int NCG, int UNITS>
__global__ __launch_bounds__(256) void gemm_bstat(
    const u16* __restrict__ A, const u16* __restrict__ B,
    u16* __restrict__ Cbf, const float* __restrict__ bgate,
    float* __restrict__ Cf, const float* __restrict__ msa,
    const u16* __restrict__ gate, const float* __restrict__ bout)
{
  __shared__ u16 sB[64 * 256];   // 32 KB, XOR-swizzled within 128B groups
  const int tid = threadIdx.x, lane = tid & 63, w = tid >> 6;
  const int g = lane >> 4, r15 = lane & 15;
  const int xcd = blockIdx.x & 7;
  const int lb = blockIdx.x >> 3;         // 0..63 per XCD
  constexpr int BPC = 64 / NCG;           // blocks per col-group
  const int cg = lb / BPC;
  const int r0 = (lb % BPC) * UNITS;      // local row-tile base (within XCD's 32)
  const int bcol = cg * 64;

  // stage B tile; source pre-swizzled so linear LDS dest + XOR read match
  #pragma unroll
  for (int i = 0; i < 8; ++i) {
    int c = i * 256 + tid;                // chunk 0..2047 (16B each)
    int col = c >> 5, s = c & 31;
    int lc = (s & 24) | ((s ^ col) & 7);  // logical chunk stored at slot s
    GLOAD16(B + (size_t)(bcol + col) * 256 + lc * 8, &sB[c * 8]);
  }

  // hoisted epilogue constants
  float gb[4] = {0.f, 0.f, 0.f, 0.f};
  if (EPI == 0 && cg >= (NCG * 3) / 4) {
    #pragma unroll
    for (int n = 0; n < 4; ++n) gb[n] = bgate[bcol - 768 + n * 16 + r15];
  }
  float bo[4] = {0.f, 0.f, 0.f, 0.f};
  if (EPI == 1) {
    #pragma unroll
    for (int n = 0; n < 4; ++n) bo[n] = bout[bcol + n * 16 + r15];
  }

  bf16x8 afA[2][8], afB[2][8];

  auto load_af = [&](int u, bf16x8 dst[2][8]) {
    const size_t brow = (size_t)(xcd * 32 + r0 + u) * 128;
    #pragma unroll
    for (int m = 0; m < 2; ++m) {
      const size_t arow = brow + w * 32 + m * 16 + r15;
      #pragma unroll
      for (int kk = 0; kk < 8; ++kk)
        dst[m][kk] = *(const bf16x8*)(A + arow * 256 + kk * 32 + g * 8);
    }
  };

  auto compute_store = [&](int u, bf16x8 af[2][8]) {
    f32x4 acc[2][4] = {};
    #pragma unroll
    for (int kk = 0; kk < 8; ++kk) {
      bf16x8 bfr[4];
      #pragma unroll
      for (int n = 0; n < 4; ++n) {
        int col = n * 16 + r15;
        int lcq = kk * 4 + g;
        int s = (lcq & 24) | ((lcq ^ col) & 7);
        bfr[n] = *(const bf16x8*)&sB[col * 256 + s * 8];
      }
      #pragma unroll
      for (int m = 0; m < 2; ++m)
        #pragma unroll
        for (int n = 0; n < 4; ++n)
          acc[m][n] = __builtin_amdgcn_mfma_f32_16x16x32_bf16(af[m][kk], bfr[n], acc[m][n], 0, 0, 0);
    }
    const int browi = (xcd * 32 + r0 + u) * 128;
    #pragma unroll
    for (int m = 0; m < 2; ++m) {
      const int row0 = browi + w * 32 + m * 16 + g * 4;
      #pragma unroll
      for (int n = 0; n < 4; ++n) {
        const int col = bcol + n * 16 + r15;
        #pragma unroll
        for (int rr = 0; rr < 4; ++rr) {
          float v = acc[m][n][rr];
          const size_t orow = (size_t)(row0 + rr);
          if (EPI == 0) {
            if (cg < NCG / 4) v *= 0.17677669529663687f * LOG2E;  // q
            else if (cg >= (NCG * 3) / 4)                         // gate
              v = 1.0f / (1.0f + __expf(-(v + gb[n])));
            Cbf[orow * 1024 + col] = f2bf(v);
          } else {
            v += bo[n];
            float gg = bf2f(gate[orow * 1024 + col]);
            Cf[orow * 256 + col] = msa[orow * 256 + col] + gg * v;
          }
        }
      }
    }
  };

  load_af(0, afA);
  __syncthreads();
  #pragma unroll
  for (int u = 0; u < UNITS; u += 2) {
    if (u + 1 < UNITS) load_af(u + 1, afB);
    compute_store(u, afA);
    if (u + 2 < UNITS) load_af(u + 2, afA);
    compute_store(u + 1, afB);
  }
}

// --------------------------------------------------------- attention
// 2048 blocks, XCD-aware: h = blk&7 (bias/K/V L2-resident per XCD).
// Block = 128 q rows, 4 waves x 32 q. Swapped QK^T (mfma(K,Q) -> S^T: lane
// holds q=r15, keys at (g,reg)) so P stays IN REGISTERS: pure-C RNE packing
// (pack2bf) builds the PV A-operand directly; V's LDS key order is permuted at
// staging to match (key<->k-slot mapping inside the MFMA is a shared bijection).
// No P LDS tile, no barriers in the loop, lane-local softmax denominator.
__global__ __launch_bounds__(256) void attn_kernel(
    const u16* __restrict__ qkvg, const u16* __restrict__ biasQ,
    u16* __restrict__ attn_out)
{
  __shared__ u16 sVt[32 * 264];      // V^T, padded rows, permuted key order
  const int blk = blockIdx.x;
  const int h = blk & 7;             // head == XCD
  const int idx2 = blk >> 3;
  const int qh = idx2 & 1;
  const int b = idx2 >> 1;
  const int tid = threadIdx.x, lane = tid & 63, w = tid >> 6;
  const int g = lane >> 4, r15 = lane & 15;
  const size_t rowbase = (size_t)b * 256;
  const int qbase = qh * 128;

  // stage V^T; key tid stored at permuted column pos so that position
  // kb*32 + g*8 + j holds key kb*32 + (j>>2)*16 + g*4 + (j&3) — the exact
  // register order of the in-register P fragment below.
  {
    const int nl = (tid >> 4) & 3, q4 = tid & 15;
    const int pos = (tid >> 6) * 64 + (nl >> 1) * 32 + (q4 >> 2) * 8 + (nl & 1) * 4 + (q4 & 3);
    const uint4* vr4 = (const uint4*)(qkvg + (rowbase + tid) * 1024 + 512 + h * 32);
    #pragma unroll
    for (int c = 0; c < 4; ++c) {
      uint4 vv = vr4[c];
      unsigned uu[4] = {vv.x, vv.y, vv.z, vv.w};
      #pragma unroll
      for (int p = 0; p < 4; ++p) {
        sVt[(c * 8 + p * 2    ) * 264 + pos] = (u16)(uu[p] & 0xffffu);
        sVt[(c * 8 + p * 2 + 1) * 264 + pos] = (u16)(uu[p] >> 16);
      }
    }
  }

  const int qrel0 = qbase + w * 32 + r15;
  // Q fragments straight from global (already scaled by log2e/sqrt(32))
  bf16x8 qf[2];
  #pragma unroll
  for (int m = 0; m < 2; ++m)
    qf[m] = *(const bf16x8*)(qkvg + (rowbase + qrel0 + m * 16) * 1024 + h * 32 + g * 8);
  __syncthreads();

  f32x4 oacc[2][2] = {};
  float lrun[2] = {0.f, 0.f};
  const u16* biasH = biasQ + (size_t)h * 65536;

  // prefetch jb=0 K fragments + bias (bf16, 8B per frag)
  bf16x8 kf[4];
  ushort4 bvu[2][4];
  #pragma unroll
  for (int n = 0; n < 4; ++n)
    kf[n] = *(const bf16x8*)(qkvg + (rowbase + n * 16 + r15) * 1024 + 256 + h * 32 + g * 8);
  #pragma unroll
  for (int m = 0; m < 2; ++m)
    #pragma unroll
    for (int n = 0; n < 4; ++n)
      bvu[m][n] = *(const ushort4*)(biasH + (size_t)(qrel0 + m * 16) * 256 + n * 16 + g * 4);

  for (int jb = 0; jb < 4; ++jb) {
    // S^T = K.Q^T: lane holds S[q = qrel0 + m*16][key = jb*64 + n*16 + g*4 + rr]
    f32x4 s[2][4];
    #pragma unroll
    for (int m = 0; m < 2; ++m) {
      #pragma unroll
      for (int n = 0; n < 4; ++n) {
        f32x4 z = {0.f, 0.f, 0.f, 0.f};
        s[m][n] = __builtin_amdgcn_mfma_f32_16x16x32_bf16(kf[n], qf[m], z, 0, 0, 0);
        const u16* bb = (const u16*)&bvu[m][n];
        #pragma unroll
        for (int rr = 0; rr < 4; ++rr) s[m][n][rr] += bf2f(bb[rr]);
      }
    }
    // prefetch next jb (loads overlap exp+PV below)
    if (jb < 3) {
      const int j1 = jb + 1;
      #pragma unroll
      for (int n = 0; n < 4; ++n)
        kf[n] = *(const bf16x8*)(qkvg + (rowbase + j1 * 64 + n * 16 + r15) * 1024 + 256 + h * 32 + g * 8);
      #pragma unroll
      for (int m = 0; m < 2; ++m)
        #pragma unroll
        for (int n = 0; n < 4; ++n)
          bvu[m][n] = *(const ushort4*)(biasH + (size_t)(qrel0 + m * 16) * 256 + j1 * 64 + n * 16 + g * 4);
    }
    // P = exp2(S): lane-local denominator (all 16 values belong to q=r15)
    unsigned pk[2][4][2];
    #pragma unroll
    for (int m = 0; m < 2; ++m) {
      #pragma unroll
      for (int n = 0; n < 4; ++n) {
        #pragma unroll
        for (int rr = 0; rr < 4; ++rr) {
          float p = __builtin_amdgcn_exp2f(s[m][n][rr]);
          s[m][n][rr] = p;
          lrun[m] += p;
        }
        pk[m][n][0] = pack2bf(s[m][n][0], s[m][n][1]);
        pk[m][n][1] = pack2bf(s[m][n][2], s[m][n][3]);
      }
    }
    // PV: P already in A-fragment layout; V read in matching permuted order
    #pragma unroll
    for (int kb = 0; kb < 2; ++kb) {
      bf16x8 vt[2];
      #pragma unroll
      for (int nd = 0; nd < 2; ++nd)
        vt[nd] = *(const bf16x8*)&sVt[(nd * 16 + r15) * 264 + jb * 64 + kb * 32 + g * 8];
      #pragma unroll
      for (int m = 0; m < 2; ++m) {
        union { unsigned u[4]; bf16x8 v; } pu;
        pu.u[0] = pk[m][2 * kb][0];     pu.u[1] = pk[m][2 * kb][1];
        pu.u[2] = pk[m][2 * kb + 1][0]; pu.u[3] = pk[m][2 * kb + 1][1];
        #pragma unroll
        for (int nd = 0; nd < 2; ++nd)
          oacc[m][nd] = __builtin_amdgcn_mfma_f32_16x16x32_bf16(pu.v, vt[nd], oacc[m][nd], 0, 0, 0);
      }
    }
  }

  // denominator: reduce across the 4 g-groups (bits 4,5), then redistribute
  // to the C-layout q index (g*4+rr) via one shuffle per rr.
  #pragma unroll
  for (int m = 0; m < 2; ++m) {
    float l = lrun[m];
    l += __shfl_xor(l, 16);
    l += __shfl_xor(l, 32);
    const float inv = 1.0f / l;
    #pragma unroll
    for (int rr = 0; rr < 4; ++rr) {
      const float invq = __shfl(inv, g * 4 + rr);
      const size_t qrow = rowbase + qbase + w * 32 + m * 16 + g * 4 + rr;
      #pragma unroll
      for (int nd = 0; nd < 2; ++nd)
        attn_out[qrow * 256 + h * 32 + nd * 16 + r15] = f2bf(oacc[m][nd][rr] * invq);
    }
  }
}

// ------------------------------------------------------------------- launcher
extern "C" void kernel_launch(void* const* d_in, const int* in_sizes, int n_in,
                              void* d_out, int out_size, void* d_ws, size_t ws_size,
                              hipStream_t stream)
{
  (void)in_sizes; (void)n_in; (void)out_size; (void)ws_size;
  const float* msa        = (const float*)d_in[0];
  const float* pair       = (const float*)d_in[1];
  const float* ln_m_scale = (const float*)d_in[2];
  const float* ln_m_bias  = (const float*)d_in[3];
  const float* ln_z_scale = (const float*)d_in[4];
  const float* ln_z_bias  = (const float*)d_in[5];
  const float* w_q        = (const float*)d_in[6];
  const float* w_k        = (const float*)d_in[7];
  const float* w_v        = (const float*)d_in[8];
  const float* w_b        = (const float*)d_in[9];
  const float* w_out      = (const float*)d_in[10];
  const float* b_out      = (const float*)d_in[11];
  const float* w_gate     = (const float*)d_in[12];
  const float* b_gate     = (const float*)d_in[13];

  char* ws = (char*)d_ws;
  u16*   m_bf   = (u16*)(ws);                    // 32768*256 bf16   = 16 MB
  u16*   wcat   = (u16*)(ws + 16777216);         // 1024*256 bf16    = 0.5 MB
  u16*   wobf   = (u16*)(ws + 17301504);         // 256*256 bf16
  u16*   qkvg   = (u16*)(ws + 17432576);         // 32768*1024 bf16  = 64 MB
  u16*   biasQ  = (u16*)(ws + 84541440);         // 8*256*256 bf16   = 1 MB
  u16*   attn_o = (u16*)(ws + 86638592);         // 32768*256 bf16   = 16 MB
  float* out = (float*)d_out;

  cast_w_kernel<<<dim3(320), dim3(256), 0, stream>>>(w_q, w_k, w_v, w_gate, w_out, wcat, wobf);
  ln_msa_kernel<<<dim3(8192), dim3(256), 0, stream>>>(msa, ln_m_scale, ln_m_bias, m_bf);
  ln_pair_bias_kernel<<<dim3(16384), dim3(256), 0, stream>>>(pair, ln_z_scale, ln_z_bias, w_b, biasQ);
  gemm_bstat<0, 16, 8><<<dim3(512), dim3(256), 0, stream>>>(m_bf, wcat, qkvg, b_gate,
                                                            nullptr, nullptr, nullptr, nullptr);
  attn_kernel<<<dim3(2048), dim3(256), 0, stream>>>(qkvg, biasQ, attn_o);
  gemm_bstat<1, 4, 2><<<dim3(512), dim3(256), 0, stream>>>(attn_o, wobf, nullptr, nullptr,
                                                           out, msa, qkvg + 768, b_out);
}

// Round 7
// 194.031 us; speedup vs baseline: 1.2469x; 1.2469x over previous
//
#include <hip/hip_runtime.h>

typedef unsigned short u16;
typedef float f32x4 __attribute__((ext_vector_type(4)));
typedef __bf16 bf16x8 __attribute__((ext_vector_type(8)));

__device__ __forceinline__ u16 f2bf(float f) {
  union { float f; unsigned u; } v; v.f = f;
  unsigned r = (v.u + 0x7fffu + ((v.u >> 16) & 1u)) >> 16;
  return (u16)r;
}
__device__ __forceinline__ float bf2f(u16 h) {
  union { unsigned u; float f; } v; v.u = ((unsigned)h) << 16; return v.f;
}
// pack two f32 -> one u32 of 2x bf16 (lo=a, hi=b) in pure C (no ISA assumption)
__device__ __forceinline__ unsigned pack2bf(float a, float b) {
  return ((unsigned)f2bf(b) << 16) | (unsigned)f2bf(a);
}

#define GLOAD16(gp, lp)                                                        \
  __builtin_amdgcn_global_load_lds(                                            \
      (const __attribute__((address_space(1))) void*)(gp),                     \
      (__attribute__((address_space(3))) void*)(lp), 16, 0, 0)

#define LOG2E 1.4426950408889634f

// ---------------------------------------------------------------- cast weights
__global__ __launch_bounds__(256) void cast_w_kernel(
    const float* __restrict__ wq, const float* __restrict__ wk,
    const float* __restrict__ wv, const float* __restrict__ wg,
    const float* __restrict__ wo, u16* __restrict__ wcat, u16* __restrict__ wobf)
{
  int idx = blockIdx.x * 256 + threadIdx.x;   // 320 blocks -> 81920 threads
  int e = idx * 4;                            // 4 floats each
  int row = e >> 8;
  int col = e & 255;
  const float* src = (row < 256)  ? (wq + (size_t)row * 256)
                   : (row < 512)  ? (wk + (size_t)(row - 256) * 256)
                   : (row < 768)  ? (wv + (size_t)(row - 512) * 256)
                   : (row < 1024) ? (wg + (size_t)(row - 768) * 256)
                                  : (wo + (size_t)(row - 1024) * 256);
  float4 v = *(const float4*)(src + col);
  ushort4 o;
  o.x = f2bf(v.x); o.y = f2bf(v.y); o.z = f2bf(v.z); o.w = f2bf(v.w);
  if (row < 1024) *(ushort4*)(wcat + e) = o;
  else            *(ushort4*)(wobf + (e - 262144)) = o;
}

// ---------------------------------------------------------------- LN(msa)->bf16
__global__ __launch_bounds__(256) void ln_msa_kernel(
    const float* __restrict__ x, const float* __restrict__ sc,
    const float* __restrict__ bi, u16* __restrict__ mo)
{
  const int row  = blockIdx.x * 4 + (threadIdx.x >> 6);
  const int lane = threadIdx.x & 63;
  const float4 v = *(const float4*)(x + (size_t)row * 256 + lane * 4);
  float s = v.x + v.y + v.z + v.w;
  #pragma unroll
  for (int off = 1; off < 64; off <<= 1) s += __shfl_xor(s, off);
  const float mu = s * 0.00390625f;
  const float d0 = v.x - mu, d1 = v.y - mu, d2 = v.z - mu, d3 = v.w - mu;
  float vs = d0*d0 + d1*d1 + d2*d2 + d3*d3;
  #pragma unroll
  for (int off = 1; off < 64; off <<= 1) vs += __shfl_xor(vs, off);
  const float rstd = rsqrtf(vs * 0.00390625f + 1e-5f);
  const float4 scv = *(const float4*)(sc + lane * 4);
  const float4 biv = *(const float4*)(bi + lane * 4);
  ushort4 o;
  o.x = f2bf(d0 * rstd * scv.x + biv.x);
  o.y = f2bf(d1 * rstd * scv.y + biv.y);
  o.z = f2bf(d2 * rstd * scv.z + biv.z);
  o.w = f2bf(d3 * rstd * scv.w + biv.w);
  *(ushort4*)(mo + (size_t)row * 256 + lane * 4) = o;
}

// ------------------------------------------- LN(pair) + einsum('ijc,hc->hij')
// Writes bias NATURAL layout, bf16, pre-scaled by log2(e): biasQ[h][i=q][j=key]
__global__ __launch_bounds__(256) void ln_pair_bias_kernel(
    const float* __restrict__ pair, const float* __restrict__ sc,
    const float* __restrict__ bi, const float* __restrict__ wb,
    u16* __restrict__ biasQ)
{
  __shared__ float swb[1024];
  #pragma unroll
  for (int i = 0; i < 4; ++i) swb[i * 256 + threadIdx.x] = wb[i * 256 + threadIdx.x];
  __syncthreads();
  const int ij   = blockIdx.x * 4 + (threadIdx.x >> 6);   // 0..65535
  const int lane = threadIdx.x & 63;
  const float2 v = *(const float2*)(pair + (size_t)ij * 128 + lane * 2);
  float s = v.x + v.y;
  #pragma unroll
  for (int off = 1; off < 64; off <<= 1) s += __shfl_xor(s, off);
  const float mu = s * 0.0078125f;
  const float d0 = v.x - mu, d1 = v.y - mu;
  float vs = d0*d0 + d1*d1;
  #pragma unroll
  for (int off = 1; off < 64; off <<= 1) vs += __shfl_xor(vs, off);
  const float rstd = rsqrtf(vs * 0.0078125f + 1e-5f);
  const float2 scv = *(const float2*)(sc + lane * 2);
  const float2 biv = *(const float2*)(bi + lane * 2);
  const float z0 = d0 * rstd * scv.x + biv.x;
  const float z1 = d1 * rstd * scv.y + biv.y;
  float a[8];
  #pragma unroll
  for (int hh = 0; hh < 8; ++hh)
    a[hh] = z0 * swb[hh * 128 + lane * 2] + z1 * swb[hh * 128 + lane * 2 + 1];
  #pragma unroll
  for (int off = 1; off < 64; off <<= 1) {
    #pragma unroll
    for (int hh = 0; hh < 8; ++hh) a[hh] += __shfl_xor(a[hh], off);
  }
  if (lane == 0) {
    const int i = ij >> 8, j = ij & 255;
    #pragma unroll
    for (int hh = 0; hh < 8; ++hh) biasQ[hh * 65536 + i * 256 + j] = f2bf(a[hh] * LOG2E);
  }
}

// ------------------------------- B-stationary small-K GEMM, vectorized epilogue
// C(M x 64*NCG) = A(M x 256) * B^T. B tile (64 cols x 256 K = 32 KB) staged
// once per block; UNITS row-tiles of 128 rows, A frags direct global->VGPR.
// MFMA operands SWAPPED (mfma(b,a)) so each lane holds 4 CONSECUTIVE OUTPUT
// COLS of one row -> ushort4/float4 epilogue, fully-coalesced wave stores.
// A rows partitioned per-XCD (2 MB slice -> L2 resident).
// EPI 0: qkvg epilogue (scale q by log2e/sqrt32, sigmoid gate); EPI 1: residual
template<int EPI, int NCG, int UNITS>
__global__ __launch_bounds__(256) void gemm_bstat(
    const u16* __restrict__ A, const u16* __restrict__ B,
    u16* __restrict__ Cbf, const float* __restrict__ bgate,
    float* __restrict__ Cf, const float* __restrict__ msa,
    const u16* __restrict__ gate, const float* __restrict__ bout)
{
  __shared__ u16 sB[64 * 256];   // 32 KB, XOR-swizzled within 128B groups
  const int tid = threadIdx.x, lane = tid & 63, w = tid >> 6;
  const int g = lane >> 4, r15 = lane & 15;
  const int xcd = blockIdx.x & 7;
  const int lb = blockIdx.x >> 3;         // local block on this XCD
  const int cg = lb % NCG;                // col-group (fast-varying -> A reuse)
  const int r0 = (lb / NCG) * UNITS;      // local row-tile base (0..31)
  const int bcol = cg * 64;

  // stage B tile; source pre-swizzled so linear LDS dest + XOR read match
  #pragma unroll
  for (int i = 0; i < 8; ++i) {
    int c = i * 256 + tid;                // chunk 0..2047 (16B each)
    int col = c >> 5, s = c & 31;
    int lc = (s & 24) | ((s ^ col) & 7);  // logical chunk stored at slot s
    GLOAD16(B + (size_t)(bcol + col) * 256 + lc * 8, &sB[c * 8]);
  }

  // hoisted per-lane epilogue constants (4 consecutive cols per lane)
  f32x4 gb4[4], bo4[4];
  if (EPI == 0 && cg >= (NCG * 3) / 4) {
    #pragma unroll
    for (int n = 0; n < 4; ++n)
      gb4[n] = *(const f32x4*)(bgate + bcol - 768 + n * 16 + g * 4);
  }
  if (EPI == 1) {
    #pragma unroll
    for (int n = 0; n < 4; ++n)
      bo4[n] = *(const f32x4*)(bout + bcol + n * 16 + g * 4);
  }

  #pragma unroll
  for (int u = 0; u < UNITS; ++u) {
    const int browi = (xcd * 32 + r0 + u) * 128;
    // A fragments direct from global (u=0 loads issued before the barrier:
    // latency hides under the B-stage vmcnt drain)
    bf16x8 af[2][8];
    #pragma unroll
    for (int m = 0; m < 2; ++m) {
      const size_t arow = (size_t)browi + w * 32 + m * 16 + r15;
      #pragma unroll
      for (int kk = 0; kk < 8; ++kk)
        af[m][kk] = *(const bf16x8*)(A + arow * 256 + kk * 32 + g * 8);
    }
    if (u == 0) __syncthreads();

    f32x4 acc[2][4] = {};
    #pragma unroll
    for (int kk = 0; kk < 8; ++kk) {
      bf16x8 bfr[4];
      #pragma unroll
      for (int n = 0; n < 4; ++n) {
        int col = n * 16 + r15;
        int lcq = kk * 4 + g;
        int s = (lcq & 24) | ((lcq ^ col) & 7);
        bfr[n] = *(const bf16x8*)&sB[col * 256 + s * 8];
      }
      // SWAPPED operands: 1st operand (bfr) -> (g,rr) axis = output cols,
      // 2nd (af) -> r15 axis = output rows.
      #pragma unroll
      for (int m = 0; m < 2; ++m)
        #pragma unroll
        for (int n = 0; n < 4; ++n)
          acc[m][n] = __builtin_amdgcn_mfma_f32_16x16x32_bf16(bfr[n], af[m][kk], acc[m][n], 0, 0, 0);
    }

    // vectorized epilogue: lane owns C[row = browi+w*32+m*16+r15]
    //                                [cols = bcol+n*16+g*4 .. +3]
    #pragma unroll
    for (int m = 0; m < 2; ++m) {
      const size_t row = (size_t)browi + w * 32 + m * 16 + r15;
      #pragma unroll
      for (int n = 0; n < 4; ++n) {
        const int col = bcol + n * 16 + g * 4;
        f32x4 v = acc[m][n];
        if (EPI == 0) {
          if (cg < NCG / 4) {
            #pragma unroll
            for (int rr = 0; rr < 4; ++rr) v[rr] *= 0.17677669529663687f * LOG2E;
          } else if (cg >= (NCG * 3) / 4) {
            #pragma unroll
            for (int rr = 0; rr < 4; ++rr)
              v[rr] = 1.0f / (1.0f + __expf(-(v[rr] + gb4[n][rr])));
          }
          ushort4 o;
          o.x = f2bf(v[0]); o.y = f2bf(v[1]); o.z = f2bf(v[2]); o.w = f2bf(v[3]);
          *(ushort4*)(Cbf + row * 1024 + col) = o;
        } else {
          ushort4 gg = *(const ushort4*)(gate + row * 1024 + col);
          f32x4 ms = *(const f32x4*)(msa + row * 256 + col);
          f32x4 o;
          o[0] = ms[0] + bf2f(gg.x) * (v[0] + bo4[n][0]);
          o[1] = ms[1] + bf2f(gg.y) * (v[1] + bo4[n][1]);
          o[2] = ms[2] + bf2f(gg.z) * (v[2] + bo4[n][2]);
          o[3] = ms[3] + bf2f(gg.w) * (v[3] + bo4[n][3]);
          *(f32x4*)(Cf + row * 256 + col) = o;
        }
      }
    }
  }
}

// --------------------------------------------------------- attention
// 2048 blocks, XCD-aware: h = blk&7 (bias/K/V L2-resident per XCD).
// Block = 128 q rows, 4 waves x 32 q. Swapped QK^T (mfma(K,Q) -> S^T: lane
// holds q=r15, keys at (g,reg)) so P stays IN REGISTERS: pure-C RNE packing
// (pack2bf) builds the PV A-operand directly; V's LDS key order is permuted at
// staging to match (key<->k-slot mapping inside the MFMA is a shared bijection).
// No P LDS tile, no barriers in the loop, lane-local softmax denominator.
__global__ __launch_bounds__(256) void attn_kernel(
    const u16* __restrict__ qkvg, const u16* __restrict__ biasQ,
    u16* __restrict__ attn_out)
{
  __shared__ u16 sVt[32 * 264];      // V^T, padded rows, permuted key order
  const int blk = blockIdx.x;
  const int h = blk & 7;             // head == XCD
  const int idx2 = blk >> 3;
  const int qh = idx2 & 1;
  const int b = idx2 >> 1;
  const int tid = threadIdx.x, lane = tid & 63, w = tid >> 6;
  const int g = lane >> 4, r15 = lane & 15;
  const size_t rowbase = (size_t)b * 256;
  const int qbase = qh * 128;

  // stage V^T; key tid stored at permuted column pos so that position
  // kb*32 + g*8 + j holds key kb*32 + (j>>2)*16 + g*4 + (j&3) — the exact
  // register order of the in-register P fragment below.
  {
    const int nl = (tid >> 4) & 3, q4 = tid & 15;
    const int pos = (tid >> 6) * 64 + (nl >> 1) * 32 + (q4 >> 2) * 8 + (nl & 1) * 4 + (q4 & 3);
    const uint4* vr4 = (const uint4*)(qkvg + (rowbase + tid) * 1024 + 512 + h * 32);
    #pragma unroll
    for (int c = 0; c < 4; ++c) {
      uint4 vv = vr4[c];
      unsigned uu[4] = {vv.x, vv.y, vv.z, vv.w};
      #pragma unroll
      for (int p = 0; p < 4; ++p) {
        sVt[(c * 8 + p * 2    ) * 264 + pos] = (u16)(uu[p] & 0xffffu);
        sVt[(c * 8 + p * 2 + 1) * 264 + pos] = (u16)(uu[p] >> 16);
      }
    }
  }

  const int qrel0 = qbase + w * 32 + r15;
  // Q fragments straight from global (already scaled by log2e/sqrt(32))
  bf16x8 qf[2];
  #pragma unroll
  for (int m = 0; m < 2; ++m)
    qf[m] = *(const bf16x8*)(qkvg + (rowbase + qrel0 + m * 16) * 1024 + h * 32 + g * 8);
  __syncthreads();

  f32x4 oacc[2][2] = {};
  float lrun[2] = {0.f, 0.f};
  const u16* biasH = biasQ + (size_t)h * 65536;

  // prefetch jb=0 K fragments + bias (bf16, 8B per frag)
  bf16x8 kf[4];
  ushort4 bvu[2][4];
  #pragma unroll
  for (int n = 0; n < 4; ++n)
    kf[n] = *(const bf16x8*)(qkvg + (rowbase + n * 16 + r15) * 1024 + 256 + h * 32 + g * 8);
  #pragma unroll
  for (int m = 0; m < 2; ++m)
    #pragma unroll
    for (int n = 0; n < 4; ++n)
      bvu[m][n] = *(const ushort4*)(biasH + (size_t)(qrel0 + m * 16) * 256 + n * 16 + g * 4);

  for (int jb = 0; jb < 4; ++jb) {
    // S^T = K.Q^T: lane holds S[q = qrel0 + m*16][key = jb*64 + n*16 + g*4 + rr]
    f32x4 s[2][4];
    #pragma unroll
    for (int m = 0; m < 2; ++m) {
      #pragma unroll
      for (int n = 0; n < 4; ++n) {
        f32x4 z = {0.f, 0.f, 0.f, 0.f};
        s[m][n] = __builtin_amdgcn_mfma_f32_16x16x32_bf16(kf[n], qf[m], z, 0, 0, 0);
        const u16* bb = (const u16*)&bvu[m][n];
        #pragma unroll
        for (int rr = 0; rr < 4; ++rr) s[m][n][rr] += bf2f(bb[rr]);
      }
    }
    // prefetch next jb (loads overlap exp+PV below)
    if (jb < 3) {
      const int j1 = jb + 1;
      #pragma unroll
      for (int n = 0; n < 4; ++n)
        kf[n] = *(const bf16x8*)(qkvg + (rowbase + j1 * 64 + n * 16 + r15) * 1024 + 256 + h * 32 + g * 8);
      #pragma unroll
      for (int m = 0; m < 2; ++m)
        #pragma unroll
        for (int n = 0; n < 4; ++n)
          bvu[m][n] = *(const ushort4*)(biasH + (size_t)(qrel0 + m * 16) * 256 + j1 * 64 + n * 16 + g * 4);
    }
    // P = exp2(S): lane-local denominator (all 16 values belong to q=r15)
    unsigned pk[2][4][2];
    #pragma unroll
    for (int m = 0; m < 2; ++m) {
      #pragma unroll
      for (int n = 0; n < 4; ++n) {
        #pragma unroll
        for (int rr = 0; rr < 4; ++rr) {
          float p = __builtin_amdgcn_exp2f(s[m][n][rr]);
          s[m][n][rr] = p;
          lrun[m] += p;
        }
        pk[m][n][0] = pack2bf(s[m][n][0], s[m][n][1]);
        pk[m][n][1] = pack2bf(s[m][n][2], s[m][n][3]);
      }
    }
    // PV: P already in A-fragment layout; V read in matching permuted order
    #pragma unroll
    for (int kb = 0; kb < 2; ++kb) {
      bf16x8 vt[2];
      #pragma unroll
      for (int nd = 0; nd < 2; ++nd)
        vt[nd] = *(const bf16x8*)&sVt[(nd * 16 + r15) * 264 + jb * 64 + kb * 32 + g * 8];
      #pragma unroll
      for (int m = 0; m < 2; ++m) {
        union { unsigned u[4]; bf16x8 v; } pu;
        pu.u[0] = pk[m][2 * kb][0];     pu.u[1] = pk[m][2 * kb][1];
        pu.u[2] = pk[m][2 * kb + 1][0]; pu.u[3] = pk[m][2 * kb + 1][1];
        #pragma unroll
        for (int nd = 0; nd < 2; ++nd)
          oacc[m][nd] = __builtin_amdgcn_mfma_f32_16x16x32_bf16(pu.v, vt[nd], oacc[m][nd], 0, 0, 0);
      }
    }
  }

  // denominator: reduce across the 4 g-groups (bits 4,5), then redistribute
  // to the C-layout q index (g*4+rr) via one shuffle per rr.
  #pragma unroll
  for (int m = 0; m < 2; ++m) {
    float l = lrun[m];
    l += __shfl_xor(l, 16);
    l += __shfl_xor(l, 32);
    const float inv = 1.0f / l;
    #pragma unroll
    for (int rr = 0; rr < 4; ++rr) {
      const float invq = __shfl(inv, g * 4 + rr);
      const size_t qrow = rowbase + qbase + w * 32 + m * 16 + g * 4 + rr;
      #pragma unroll
      for (int nd = 0; nd < 2; ++nd)
        attn_out[qrow * 256 + h * 32 + nd * 16 + r15] = f2bf(oacc[m][nd][rr] * invq);
    }
  }
}

// ------------------------------------------------------------------- launcher
extern "C" void kernel_launch(void* const* d_in, const int* in_sizes, int n_in,
                              void* d_out, int out_size, void* d_ws, size_t ws_size,
                              hipStream_t stream)
{
  (void)in_sizes; (void)n_in; (void)out_size; (void)ws_size;
  const float* msa        = (const float*)d_in[0];
  const float* pair       = (const float*)d_in[1];
  const float* ln_m_scale = (const float*)d_in[2];
  const float* ln_m_bias  = (const float*)d_in[3];
  const float* ln_z_scale = (const float*)d_in[4];
  const float* ln_z_bias  = (const float*)d_in[5];
  const float* w_q        = (const float*)d_in[6];
  const float* w_k        = (const float*)d_in[7];
  const float* w_v        = (const float*)d_in[8];
  const float* w_b        = (const float*)d_in[9];
  const float* w_out      = (const float*)d_in[10];
  const float* b_out      = (const float*)d_in[11];
  const float* w_gate     = (const float*)d_in[12];
  const float* b_gate     = (const float*)d_in[13];

  char* ws = (char*)d_ws;
  u16*   m_bf   = (u16*)(ws);                    // 32768*256 bf16   = 16 MB
  u16*   wcat   = (u16*)(ws + 16777216);         // 1024*256 bf16    = 0.5 MB
  u16*   wobf   = (u16*)(ws + 17301504);         // 256*256 bf16
  u16*   qkvg   = (u16*)(ws + 17432576);         // 32768*1024 bf16  = 64 MB
  u16*   biasQ  = (u16*)(ws + 84541440);         // 8*256*256 bf16   = 1 MB
  u16*   attn_o = (u16*)(ws + 86638592);         // 32768*256 bf16   = 16 MB
  float* out = (float*)d_out;

  cast_w_kernel<<<dim3(320), dim3(256), 0, stream>>>(w_q, w_k, w_v, w_gate, w_out, wcat, wobf);
  ln_msa_kernel<<<dim3(8192), dim3(256), 0, stream>>>(msa, ln_m_scale, ln_m_bias, m_bf);
  ln_pair_bias_kernel<<<dim3(16384), dim3(256), 0, stream>>>(pair, ln_z_scale, ln_z_bias, w_b, biasQ);
  gemm_bstat<0, 16, 2><<<dim3(2048), dim3(256), 0, stream>>>(m_bf, wcat, qkvg, b_gate,
                                                             nullptr, nullptr, nullptr, nullptr);
  attn_kernel<<<dim3(2048), dim3(256), 0, stream>>>(qkvg, biasQ, attn_o);
  gemm_bstat<1, 4, 1><<<dim3(1024), dim3(256), 0, stream>>>(attn_o, wobf, nullptr, nullptr,
                                                            out, msa, qkvg + 768, b_out);
}